// Round 13
// baseline (178.998 us; speedup 1.0000x reference)
//
#include <hip/hip_runtime.h>

// MSDeformAttn: B=4, Lq=Lv=5440 (M=21760), C=256, heads=8, levels=4, points=4, hd=32
// Level shapes: (64,64),(32,32),(16,16),(8,8) -> starts 0,4096,5120,5376
//
// R22: consolidation — 3 dispatches -> 2.
//  - Cross-round budget: kernels sum ~96us but dur_us ~172-190; ~75-80us is
//    one 256MB re-poison fill (~42us, in every profile) + launch gaps (+-6us
//    noise run-to-run). Kernel micro-wins are below this noise. Remaining
//    controllable overhead: dispatch count.
//  - R22: prep_w deleted. gemm12 stages B by in-block strided-f32 cvt (R9/R11
//    pattern, measured same 42us wall) into the proven XOR-swizzled layout;
//    32 extra blocks on gemm12's grid write wto (consumed only by next
//    dispatch -> no intra-grid ordering assumed). sample_out = R21 verbatim.
//  - Predict: gemm12 42-46, sample_out ~52, total ~162-170 (one gap gone).
//    STOPPING RULE: if total >=172, remaining gap is harness-level; declare
//    plateau next round.

typedef __attribute__((ext_vector_type(8))) _Float16 half8;
typedef __attribute__((ext_vector_type(4))) _Float16 half4;
typedef __attribute__((ext_vector_type(4))) float f32x4;

typedef __attribute__((address_space(3))) unsigned int lds_uint;
typedef const __attribute__((address_space(1))) unsigned int g_uint;

__device__ __forceinline__ half8 splat8(_Float16 v) {
    half8 r = {v, v, v, v, v, v, v, v};
    return r;
}

#define M_TOTAL 21760

// -------- fused GEMM1+GEMM2, 64x64 tiles, one-shot K=256, one barrier ---------
// blocks 0..3399: GEMM tiles (XCD chunk swizzle). blocks 3400..3431: wto prep
// (fragment-major W_out^T for sample_out's epilogue; consumed next dispatch).
__global__ __launch_bounds__(256) void gemm12_cvt(
    const float* __restrict__ value, const float* __restrict__ query,
    const float* __restrict__ W_val, const float* __restrict__ W_off,
    const float* __restrict__ W_attn, const float* __restrict__ W_out,
    const float* __restrict__ b_val, const float* __restrict__ b_off,
    const float* __restrict__ b_attn,
    _Float16* __restrict__ valh, _Float16* __restrict__ offh,
    _Float16* __restrict__ wto)
{
    // row-major [64][256] f16 (pitch 512B), XOR-swizzled within row
    __shared__ _Float16 Asw[64 * 256];   // 32KB
    __shared__ _Float16 Bsw[64 * 256];   // 32KB

    const int tid = threadIdx.x;

    if (blockIdx.x >= 3400) {
        // ---- wto prep: slot s=((cg*8+kt)*64 + l) holds W_out[k0..k0+8)[col]
        const int s = ((int)blockIdx.x - 3400) * 256 + tid;   // 0..8191
        const int cg = s >> 9;
        const int kt = (s >> 6) & 7;
        const int l = s & 63;
        const int col = cg * 16 + (l & 15);
        const int k0 = kt * 32 + (l >> 4) * 8;
        half8 h;
#pragma unroll
        for (int e = 0; e < 8; ++e)
            h[e] = (_Float16)W_out[(k0 + e) * 256 + col];
        *(half8*)(wto + ((size_t)s << 3)) = h;
        return;
    }

    // XCD chunk swizzle: 3400 = 8 * 425
    const int bid = ((int)blockIdx.x % 8) * 425 + ((int)blockIdx.x / 8);

    const bool g1 = bid < 1360;
    const int id = g1 ? bid : bid - 1360;
    const int mt = g1 ? (id >> 2) : (id / 6);
    const int nt = g1 ? (id & 3) : (id % 6);
    const int NN = g1 ? 256 : 384;
    const float* A = g1 ? value : query;
    _Float16* C = g1 ? valh : offh;
    const int bm = mt * 64;
    const int bn = nt * 64;

    const float* W;
    int sW, nb;
    if (g1)            { W = W_val;  sW = 256; nb = bn; }
    else if (nt < 4)   { W = W_off;  sW = 256; nb = bn; }
    else               { W = W_attn; sW = 128; nb = bn - 256; }

    const int wave = tid >> 6, lane = tid & 63;
    const int ml = lane & 15, q = lane >> 4;

    // ---- B: in-block strided f32 read + cvt + swizzled LDS write ----------
    // thread: col = tid&63, k-group = tid>>6 (64 k each). Reads are 256B
    // dense per wave-instruction (64 consecutive cols). Write layout matches
    // the MFMA loop's read: byte = col*512 + ((2k) ^ ((col&7)<<4)).
    {
        const int bcol = tid & 63;
        const int bkg = tid >> 6;
        const float* wS = W + (size_t)(bkg * 64) * sW + nb + bcol;
        _Float16* bdst = Bsw + ((size_t)bcol * 512 >> 1);
        const int bswl = (bcol & 7) << 4;
#pragma unroll
        for (int u = 0; u < 8; ++u) {
            float pv[8];
#pragma unroll
            for (int e = 0; e < 8; ++e)
                pv[e] = wS[(size_t)(u * 8 + e) * sW];
            const half8 hb = {(_Float16)pv[0], (_Float16)pv[1], (_Float16)pv[2], (_Float16)pv[3],
                              (_Float16)pv[4], (_Float16)pv[5], (_Float16)pv[6], (_Float16)pv[7]};
            const int kb = (bkg * 64 + u * 8) * 2;        // k byte offset
            *(half8*)(bdst + ((kb ^ bswl) >> 1)) = hb;
        }
    }

    // ---- A: wave-private 16 rows; one full row per wave-instruction -------
    const int rbase = wave * 16;
    float4 pa[16];
#pragma unroll
    for (int rr = 0; rr < 16; ++rr)
        pa[rr] = *(const float4*)(A + (size_t)(bm + rbase + rr) * 256 + lane * 4);
#pragma unroll
    for (int rr = 0; rr < 16; ++rr) {
        const int row = rbase + rr;
        const float4 v = pa[rr];
        const half4 h = {(_Float16)v.x, (_Float16)v.y, (_Float16)v.z, (_Float16)v.w};
        const int wbyte = row * 512 + ((lane * 8) ^ ((row & 7) << 4));
        *(half4*)(Asw + (wbyte >> 1)) = h;
    }

    __syncthreads();   // the only barrier

    // ---- pure-LDS MFMA loop ----------------------------------------------
    const int swl = (ml & 7) << 4;
    const int abase = (rbase + ml) * 512;

    const f32x4 zero4 = {0.f, 0.f, 0.f, 0.f};
    f32x4 acc[4] = {zero4, zero4, zero4, zero4};

#pragma unroll
    for (int kt = 0; kt < 8; ++kt) {
        const int koff = (kt * 64 + q * 16) ^ swl;
        const half8 af = *(const half8*)(Asw + ((abase + koff) >> 1));
#pragma unroll
        for (int j = 0; j < 4; ++j) {
            const half8 bf = *(const half8*)(Bsw + ((((j * 16 + ml) * 512) + koff) >> 1));
            acc[j] = __builtin_amdgcn_mfma_f32_16x16x32_f16(af, bf, acc[j], 0, 0, 0);
        }
    }

    // ---- epilogue ---------------------------------------------------------
    const int r0 = q * 4;
#pragma unroll
    for (int j = 0; j < 4; ++j) {
        const int col = bn + j * 16 + ml;
        const float bj = g1 ? b_val[col] : (col < 256 ? b_off[col] : b_attn[col - 256]);
        const size_t rbaseC = (size_t)(bm + rbase + r0) * NN + col;
#pragma unroll
        for (int r = 0; r < 4; ++r)
            C[rbaseC + (size_t)r * NN] = (_Float16)(acc[j][r] + bj);
    }
}

// ------- fused sampler + output GEMM: 512 threads, 16 query rows per block ----
__global__ __launch_bounds__(512) void sample_out(
    const _Float16* __restrict__ valh,   // [M,256] f16
    const float* __restrict__ refp,      // [B,Lq,4,2]
    const _Float16* __restrict__ offh,   // [M,384] f16: 0-255 offsets, 256-383 logits
    const _Float16* __restrict__ wto,    // fragment-major W_out^T (8192 slots x 8)
    const float* __restrict__ b_out,     // [256] f32
    float* __restrict__ out)             // [M,256] f32
{
    __shared__ _Float16 accT[16 * 256];  // 8KB acc tile, XOR-swizzled rows

    // batch->XCD affinity (bijective over 1360 = 8 * 170)
    const int bi = (int)blockIdx.x;
    const int xcd = bi & 7, rr_ = bi >> 3;
    const int L = (xcd >> 1) * 340 + (xcd & 1) * 170 + rr_;

    const int tid = threadIdx.x;
    const int wave = tid >> 6, lane = tid & 63;
    const int q2 = lane >> 5, sl = lane & 31;
    const int bql = wave * 2 + q2;                   // local row 0..15
    const int bq = L * 16 + bql;                     // 0..21759
    const int b = bq / 5440;
    const int h = sl >> 2;          // head
    const int t = sl & 3;           // dual role: my LEVEL (scalar) and d8 octet (gather)
    const int d8 = t * 8;

    // ---------- scalar phase: lane t computes level t's 4 points ----------
    const int Wt = 64 >> t;                       // {64,32,16,8}
    const float fW = (float)Wt;

    const half8 ofr = *(const half8*)(offh + (size_t)bq * 384 + h * 32 + t * 8);
    const half4 lgt = *(const half4*)(offh + (size_t)bq * 384 + 256 + h * 16 + t * 4);
    const float2 rxy = *(const float2*)(refp + (size_t)bq * 8 + t * 2);

    float lg[4];
#pragma unroll
    for (int p = 0; p < 4; ++p) lg[p] = (float)lgt[p];

    // group softmax: 4-lane butterfly (lanes t=0..3 share (bq,h))
    float mx = fmaxf(fmaxf(lg[0], lg[1]), fmaxf(lg[2], lg[3]));
    mx = fmaxf(mx, __shfl_xor(mx, 1));
    mx = fmaxf(mx, __shfl_xor(mx, 2));
    float s = 0.f;
#pragma unroll
    for (int p = 0; p < 4; ++p) { lg[p] = __expf(lg[p] - mx); s += lg[p]; }
    s += __shfl_xor(s, 1);
    s += __shfl_xor(s, 2);
    const float inv = 1.f / s;

    // per-corner pack: row(<=4095) << 16 | f16(weight)
    unsigned pk[16];
#pragma unroll
    for (int p = 0; p < 4; ++p) {
        const float aw = lg[p] * inv;
        const float ox = (float)ofr[p * 2];
        const float oy = (float)ofr[p * 2 + 1];
        const float x = fmaf(rxy.x, fW, ox) - 0.5f;
        const float y = fmaf(rxy.y, fW, oy) - 0.5f;
        const float x0f = floorf(x), y0f = floorf(y);
        const int x0 = (int)x0f, y0 = (int)y0f;
        const float wx = x - x0f, wy = y - y0f;
        const bool okx0 = ((unsigned)x0 < (unsigned)Wt);
        const bool okx1 = ((unsigned)(x0 + 1) < (unsigned)Wt);
        const bool oky0 = ((unsigned)y0 < (unsigned)Wt);
        const bool oky1 = ((unsigned)(y0 + 1) < (unsigned)Wt);
        const int xc0 = min(max(x0, 0), Wt - 1);
        const int xc1 = min(max(x0 + 1, 0), Wt - 1);
        const int yc0 = min(max(y0, 0), Wt - 1);
        const int yc1 = min(max(y0 + 1, 0), Wt - 1);
        const _Float16 w0 = (_Float16)((okx0 & oky0) ? (1.f - wx) * (1.f - wy) * aw : 0.f);
        const _Float16 w1 = (_Float16)((okx1 & oky0) ? wx * (1.f - wy) * aw : 0.f);
        const _Float16 w2 = (_Float16)((okx0 & oky1) ? (1.f - wx) * wy * aw : 0.f);
        const _Float16 w3 = (_Float16)((okx1 & oky1) ? wx * wy * aw : 0.f);
        pk[p * 4 + 0] = ((unsigned)(yc0 * Wt + xc0) << 16) |
                        (unsigned)__builtin_bit_cast(unsigned short, w0);
        pk[p * 4 + 1] = ((unsigned)(yc0 * Wt + xc1) << 16) |
                        (unsigned)__builtin_bit_cast(unsigned short, w1);
        pk[p * 4 + 2] = ((unsigned)(yc1 * Wt + xc0) << 16) |
                        (unsigned)__builtin_bit_cast(unsigned short, w2);
        pk[p * 4 + 3] = ((unsigned)(yc1 * Wt + xc1) << 16) |
                        (unsigned)__builtin_bit_cast(unsigned short, w3);
    }

    // ---------- gather phase: level-pipelined (prefetch l+1 before consume l) --
    const int gbase = lane & ~3;                  // group leader lane
    const _Float16* vb = valh + ((size_t)(b * 5440)) * 256 + h * 32 + d8;
    const _Float16* v0 = vb;                      // level 0 start 0
    const _Float16* v1 = vb + (size_t)4096 * 256;
    const _Float16* v2 = vb + (size_t)5120 * 256;
    const _Float16* v3 = vb + (size_t)5376 * 256;

    unsigned qA[16], qB[16];
    half8 cA[16], cB[16];
    half8 acc = splat8((_Float16)0.f);

#define SHUF(dst, srclane)                                                     \
    {                                                                          \
        _Pragma("unroll") for (int c = 0; c < 16; ++c)                         \
            dst[c] = (unsigned)__shfl((int)pk[c], (srclane));                  \
    }
#define ISSUE(dst, qv, vbase)                                                  \
    __builtin_amdgcn_sched_barrier(0);                                         \
    {                                                                          \
        _Pragma("unroll") for (int c = 0; c < 16; ++c)                         \
            dst[c] = *(const half8*)((vbase) + ((size_t)(qv[c] >> 16) << 8));  \
    }                                                                          \
    __builtin_amdgcn_sched_barrier(0);
#define CONSUME(cv, qv)                                                        \
    {                                                                          \
        _Pragma("unroll") for (int c = 0; c < 16; ++c)                         \
            acc += cv[c] * splat8(__builtin_bit_cast(                          \
                _Float16, (unsigned short)(qv[c] & 0xffffu)));                 \
    }

    // prologue: level 0 into A
    SHUF(qA, gbase + 0);
    ISSUE(cA, qA, v0);
    // L1 prefetch into B, consume L0
    SHUF(qB, gbase + 1);
    ISSUE(cB, qB, v1);
    CONSUME(cA, qA);
    // L2 prefetch into A, consume L1
    SHUF(qA, gbase + 2);
    ISSUE(cA, qA, v2);
    CONSUME(cB, qB);
    // L3 prefetch into B, consume L2
    SHUF(qB, gbase + 3);
    ISSUE(cB, qB, v3);
    CONSUME(cA, qA);
    // consume L3
    CONSUME(cB, qB);

#undef SHUF
#undef ISSUE
#undef CONSUME

    // ---------- acc -> swizzled LDS tile ----------------------------------
    {
        const int cbyte = (h * 32 + d8) * 2;                      // 16B aligned
        const int wbyte = bql * 512 + (cbyte ^ ((bql & 7) << 4));
        *(half8*)(accT + (wbyte >> 1)) = acc;
    }
    __syncthreads();

    // ---------- output GEMM: 16x256 @ wto (fragment-major), bias, f32 store ---
    const int ml = lane & 15, q = lane >> 4;
    const int wc0 = wave * 32;                   // wave owns cols wc0..wc0+31
    const f32x4 zero4 = {0.f, 0.f, 0.f, 0.f};
    f32x4 o[2] = {zero4, zero4};

#pragma unroll
    for (int kt = 0; kt < 8; ++kt) {
        const int koff = kt * 64 + q * 16;       // byte k-offset in acc row
        const half8 af = *(const half8*)(accT +
            ((ml * 512 + (koff ^ ((ml & 7) << 4))) >> 1));
#pragma unroll
        for (int j = 0; j < 2; ++j) {
            // fragment-major: 1KB contiguous per wave-instruction
            const half8 bf = *(const half8*)(wto +
                ((((size_t)(wave * 2 + j) * 8 + kt) * 64 + lane) << 3));
            o[j] = __builtin_amdgcn_mfma_f32_16x16x32_f16(af, bf, o[j], 0, 0, 0);
        }
    }

    const int r0 = q * 4;
    const size_t bq0 = (size_t)L * 16;
#pragma unroll
    for (int j = 0; j < 2; ++j) {
        const int col = wc0 + j * 16 + ml;
        const float bj = b_out[col];
#pragma unroll
        for (int r = 0; r < 4; ++r)
            out[(bq0 + r0 + r) * 256 + col] = o[j][r] + bj;
    }
}

extern "C" void kernel_launch(void* const* d_in, const int* in_sizes, int n_in,
                              void* d_out, int out_size, void* d_ws, size_t ws_size,
                              hipStream_t stream) {
    const float* query  = (const float*)d_in[0];
    const float* refp   = (const float*)d_in[1];
    const float* value  = (const float*)d_in[2];
    const float* W_off  = (const float*)d_in[3];
    const float* b_off  = (const float*)d_in[4];
    const float* W_attn = (const float*)d_in[5];
    const float* b_attn = (const float*)d_in[6];
    const float* W_val  = (const float*)d_in[7];
    const float* b_val  = (const float*)d_in[8];
    const float* W_out  = (const float*)d_in[9];
    const float* b_out  = (const float*)d_in[10];
    float* out = (float*)d_out;

    const size_t M = M_TOTAL;

    _Float16* valh  = (_Float16*)d_ws;                // M*256
    _Float16* offh  = valh + M * 256;                 // M*384
    _Float16* wto   = offh + M * 384;                 // 8192 slots * 8 = 65536

    dim3 blk(256);
    gemm12_cvt<<<dim3(3432), blk, 0, stream>>>(
        value, query, W_val, W_off, W_attn, W_out,
        b_val, b_off, b_attn, valh, offh, wto);
    sample_out<<<dim3(M / 16), dim3(512), 0, stream>>>(
        valh, refp, offh, wto, b_out, out);
}

// Round 14
// 166.563 us; speedup vs baseline: 1.0747x; 1.0747x over previous
//
#include <hip/hip_runtime.h>

// MSDeformAttn: B=4, Lq=Lv=5440 (M=21760), C=256, heads=8, levels=4, points=4, hd=32
// Level shapes: (64,64),(32,32),(16,16),(8,8) -> starts 0,4096,5120,5376
//
// R23 = R20 verbatim (best measured total: 171.9us). Plateau declared.
//  - 14 rounds: totals 171.9-179.0 (+-4-6us noise) UNCORRELATED with kernel
//    improvements. ~75-80us/run is harness-level (256MB re-poison fill ~42us
//    + launch gaps). Kernels latency-bound, no pipe >30%.
//  - Falsified levers: occupancy (R12/13), barriers (R10/11/16), FETCH (R16/17),
//    LDS conflicts (R16/20), TA transactions (R17), dispatch count (R18/22),
//    gather pipelining (R21). Real wins: sampler 4-lane dedup (R14),
//    batch->XCD L2 affinity + fragment-major wto (R20), fused tail (R18).
//  - Predict: total 172 +- 5us (reproduce R20). Final state.

typedef __attribute__((ext_vector_type(8))) _Float16 half8;
typedef __attribute__((ext_vector_type(4))) _Float16 half4;
typedef __attribute__((ext_vector_type(4))) float f32x4;

typedef __attribute__((address_space(3))) unsigned int lds_uint;
typedef const __attribute__((address_space(1))) unsigned int g_uint;

__device__ __forceinline__ void load_lds16(const _Float16* g, _Float16* l) {
    __builtin_amdgcn_global_load_lds((g_uint*)g, (lds_uint*)l, 16, 0, 0);
}

__device__ __forceinline__ half8 splat8(_Float16 v) {
    half8 r = {v, v, v, v, v, v, v, v};
    return r;
}

#define M_TOTAL 21760

// -------- prep_w: weights -> f16 pre-swizzled tiles + fragment-major W_out^T --
// blocks 0..79:   wtf tiles (pre-XOR-swizzled so linear DMA lands swizzled)
// blocks 80..111: wto fragment-major: slot s=((cg*8+kt)*64 + q*16+ml) holds
//                 W_out[k][col], k=kt*32+q*8..+8, col=cg*16+ml  (8192 slots)
__global__ __launch_bounds__(256) void prep_w(
    const float* __restrict__ W_val, const float* __restrict__ W_off,
    const float* __restrict__ W_attn, const float* __restrict__ W_out,
    _Float16* __restrict__ wtf, _Float16* __restrict__ wto)
{
    if (blockIdx.x >= 80) {
        const int s = (blockIdx.x - 80) * 256 + threadIdx.x;   // 0..8191
        const int cg = s >> 9;
        const int kt = (s >> 6) & 7;
        const int l = s & 63;
        const int col = cg * 16 + (l & 15);
        const int k0 = kt * 32 + (l >> 4) * 8;
        half8 h;
#pragma unroll
        for (int e = 0; e < 8; ++e)
            h[e] = (_Float16)W_out[(k0 + e) * 256 + col];
        *(half8*)(wto + ((size_t)s << 3)) = h;
        return;
    }
    const int slot = blockIdx.x * 256 + threadIdx.x;   // 0..20479
    const int T = slot >> 11;
    const int rem = slot & 2047;
    const int n = rem >> 5;            // col-in-tile 0..63
    const int k0 = (rem & 31) * 8;     // k chunk of 8
    half8 h;
#pragma unroll
    for (int e = 0; e < 8; ++e) {
        const int k = k0 + e;
        float v;
        if (T < 4) {
            v = W_val[k * 256 + T * 64 + n];
        } else {
            const int n2 = (T - 4) * 64 + n;
            v = (n2 < 256) ? W_off[k * 256 + n2] : W_attn[k * 128 + (n2 - 256)];
        }
        h[e] = (_Float16)v;
    }
    const int dbyte = T * 32768 + n * 512 + ((k0 * 2) ^ ((n & 7) << 4));
    *(half8*)(wtf + (dbyte >> 1)) = h;
}

// -------- fused GEMM1+GEMM2, 64x64 tiles, one-shot K=256, one barrier ---------
__global__ __launch_bounds__(256) void gemm12_cvt(
    const float* __restrict__ value, const float* __restrict__ query,
    const _Float16* __restrict__ wtf,
    const float* __restrict__ b_val, const float* __restrict__ b_off,
    const float* __restrict__ b_attn,
    _Float16* __restrict__ valh, _Float16* __restrict__ offh)
{
    // row-major [64][256] f16 (pitch 512B), XOR-swizzled within row
    __shared__ _Float16 Asw[64 * 256];   // 32KB
    __shared__ _Float16 Bsw[64 * 256];   // 32KB (DMA'd, pre-swizzled source)

    // XCD chunk swizzle: 3400 = 8 * 425
    const int bid = ((int)blockIdx.x % 8) * 425 + ((int)blockIdx.x / 8);

    const bool g1 = bid < 1360;
    const int id = g1 ? bid : bid - 1360;
    const int mt = g1 ? (id >> 2) : (id / 6);
    const int nt = g1 ? (id & 3) : (id % 6);
    const int NN = g1 ? 256 : 384;
    const float* A = g1 ? value : query;
    _Float16* C = g1 ? valh : offh;
    const int bm = mt * 64;
    const int bn = nt * 64;
    const int T  = g1 ? nt : 4 + nt;

    const int tid = threadIdx.x;
    const int wave = tid >> 6, lane = tid & 63;
    const int ml = lane & 15, q = lane >> 4;

    // ---- B: one linear 32KB DMA per block (512 line-requests) -------------
    const _Float16* wsrc = wtf + ((size_t)T << 14);    // T * 32768 bytes
#pragma unroll
    for (int i = 0; i < 8; ++i)
        load_lds16(wsrc + (((size_t)i * 256 + tid) << 3),
                   Bsw + (((size_t)i * 256 + wave * 64) << 3));

    // ---- A: wave-private 16 rows; one full row per wave-instruction -------
    const int rbase = wave * 16;
    float4 pa[16];
#pragma unroll
    for (int rr = 0; rr < 16; ++rr)
        pa[rr] = *(const float4*)(A + (size_t)(bm + rbase + rr) * 256 + lane * 4);
#pragma unroll
    for (int rr = 0; rr < 16; ++rr) {
        const int row = rbase + rr;
        const float4 v = pa[rr];
        const half4 h = {(_Float16)v.x, (_Float16)v.y, (_Float16)v.z, (_Float16)v.w};
        const int wbyte = row * 512 + ((lane * 8) ^ ((row & 7) << 4));
        *(half4*)(Asw + (wbyte >> 1)) = h;
    }

    __syncthreads();   // drains DMA (vmcnt) + A ds_writes (lgkm); the only barrier

    // ---- pure-LDS MFMA loop ----------------------------------------------
    const int swl = (ml & 7) << 4;
    const int abase = (rbase + ml) * 512;

    const f32x4 zero4 = {0.f, 0.f, 0.f, 0.f};
    f32x4 acc[4] = {zero4, zero4, zero4, zero4};

#pragma unroll
    for (int kt = 0; kt < 8; ++kt) {
        const int koff = (kt * 64 + q * 16) ^ swl;
        const half8 af = *(const half8*)(Asw + ((abase + koff) >> 1));
#pragma unroll
        for (int j = 0; j < 4; ++j) {
            const half8 bf = *(const half8*)(Bsw + ((((j * 16 + ml) * 512) + koff) >> 1));
            acc[j] = __builtin_amdgcn_mfma_f32_16x16x32_f16(af, bf, acc[j], 0, 0, 0);
        }
    }

    // ---- epilogue ---------------------------------------------------------
    const int r0 = q * 4;
#pragma unroll
    for (int j = 0; j < 4; ++j) {
        const int col = bn + j * 16 + ml;
        const float bj = g1 ? b_val[col] : (col < 256 ? b_off[col] : b_attn[col - 256]);
        const size_t rbaseC = (size_t)(bm + rbase + r0) * NN + col;
#pragma unroll
        for (int r = 0; r < 4; ++r)
            C[rbaseC + (size_t)r * NN] = (_Float16)(acc[j][r] + bj);
    }
}

// ------- fused sampler + output GEMM: 512 threads, 16 query rows per block ----
__global__ __launch_bounds__(512) void sample_out(
    const _Float16* __restrict__ valh,   // [M,256] f16
    const float* __restrict__ refp,      // [B,Lq,4,2]
    const _Float16* __restrict__ offh,   // [M,384] f16: 0-255 offsets, 256-383 logits
    const _Float16* __restrict__ wto,    // fragment-major W_out^T (8192 slots x 8)
    const float* __restrict__ b_out,     // [256] f32
    float* __restrict__ out)             // [M,256] f32
{
    __shared__ _Float16 accT[16 * 256];  // 8KB acc tile, XOR-swizzled rows

    // batch->XCD affinity: hardware round-robins consecutive launched ids
    // across the 8 XCDs; remap so each XCD serves one batch-half (170 blocks,
    // valh slice 2.78MB < 4MB L2). Bijective over 1360 = 8 * 170.
    const int bi = (int)blockIdx.x;
    const int xcd = bi & 7, rr_ = bi >> 3;
    const int L = (xcd >> 1) * 340 + (xcd & 1) * 170 + rr_;

    const int tid = threadIdx.x;
    const int wave = tid >> 6, lane = tid & 63;
    const int q2 = lane >> 5, sl = lane & 31;
    const int bql = wave * 2 + q2;                   // local row 0..15
    const int bq = L * 16 + bql;                     // 0..21759
    const int b = bq / 5440;
    const int h = sl >> 2;          // head
    const int t = sl & 3;           // dual role: my LEVEL (scalar) and d8 octet (gather)
    const int d8 = t * 8;

    // ---------- scalar phase: lane t computes level t's 4 points ----------
    const int Wt = 64 >> t;                       // {64,32,16,8}
    const float fW = (float)Wt;

    const half8 ofr = *(const half8*)(offh + (size_t)bq * 384 + h * 32 + t * 8);
    const half4 lgt = *(const half4*)(offh + (size_t)bq * 384 + 256 + h * 16 + t * 4);
    const float2 rxy = *(const float2*)(refp + (size_t)bq * 8 + t * 2);

    float lg[4];
#pragma unroll
    for (int p = 0; p < 4; ++p) lg[p] = (float)lgt[p];

    // group softmax: 4-lane butterfly (lanes t=0..3 share (bq,h))
    float mx = fmaxf(fmaxf(lg[0], lg[1]), fmaxf(lg[2], lg[3]));
    mx = fmaxf(mx, __shfl_xor(mx, 1));
    mx = fmaxf(mx, __shfl_xor(mx, 2));
    float s = 0.f;
#pragma unroll
    for (int p = 0; p < 4; ++p) { lg[p] = __expf(lg[p] - mx); s += lg[p]; }
    s += __shfl_xor(s, 1);
    s += __shfl_xor(s, 2);
    const float inv = 1.f / s;

    // per-corner pack: row(<=4095) << 16 | f16(weight)
    unsigned pk[16];
#pragma unroll
    for (int p = 0; p < 4; ++p) {
        const float aw = lg[p] * inv;
        const float ox = (float)ofr[p * 2];
        const float oy = (float)ofr[p * 2 + 1];
        const float x = fmaf(rxy.x, fW, ox) - 0.5f;
        const float y = fmaf(rxy.y, fW, oy) - 0.5f;
        const float x0f = floorf(x), y0f = floorf(y);
        const int x0 = (int)x0f, y0 = (int)y0f;
        const float wx = x - x0f, wy = y - y0f;
        const bool okx0 = ((unsigned)x0 < (unsigned)Wt);
        const bool okx1 = ((unsigned)(x0 + 1) < (unsigned)Wt);
        const bool oky0 = ((unsigned)y0 < (unsigned)Wt);
        const bool oky1 = ((unsigned)(y0 + 1) < (unsigned)Wt);
        const int xc0 = min(max(x0, 0), Wt - 1);
        const int xc1 = min(max(x0 + 1, 0), Wt - 1);
        const int yc0 = min(max(y0, 0), Wt - 1);
        const int yc1 = min(max(y0 + 1, 0), Wt - 1);
        const _Float16 w0 = (_Float16)((okx0 & oky0) ? (1.f - wx) * (1.f - wy) * aw : 0.f);
        const _Float16 w1 = (_Float16)((okx1 & oky0) ? wx * (1.f - wy) * aw : 0.f);
        const _Float16 w2 = (_Float16)((okx0 & oky1) ? (1.f - wx) * wy * aw : 0.f);
        const _Float16 w3 = (_Float16)((okx1 & oky1) ? wx * wy * aw : 0.f);
        pk[p * 4 + 0] = ((unsigned)(yc0 * Wt + xc0) << 16) |
                        (unsigned)__builtin_bit_cast(unsigned short, w0);
        pk[p * 4 + 1] = ((unsigned)(yc0 * Wt + xc1) << 16) |
                        (unsigned)__builtin_bit_cast(unsigned short, w1);
        pk[p * 4 + 2] = ((unsigned)(yc1 * Wt + xc0) << 16) |
                        (unsigned)__builtin_bit_cast(unsigned short, w2);
        pk[p * 4 + 3] = ((unsigned)(yc1 * Wt + xc1) << 16) |
                        (unsigned)__builtin_bit_cast(unsigned short, w3);
    }

    // ---------- gather phase: all lanes, per level, via group exchange ----
    const int starts_[4] = {0, 4096, 5120, 5376};
    const int gbase = lane & ~3;                  // group leader lane

    half8 acc = splat8((_Float16)0.f);
#pragma unroll
    for (int l = 0; l < 4; ++l) {
        const _Float16* vbase = valh + ((size_t)(b * 5440 + starts_[l])) * 256 + h * 32 + d8;
        const int src = gbase + l;

        unsigned q_[16];
#pragma unroll
        for (int c = 0; c < 16; ++c)
            q_[c] = (unsigned)__shfl((int)pk[c], src);

        // pin: all 16 loads issue before any consumer (progressive vmcnt drain)
        __builtin_amdgcn_sched_barrier(0);
        half8 c_[16];
#pragma unroll
        for (int c = 0; c < 16; ++c)
            c_[c] = *(const half8*)(vbase + ((size_t)(q_[c] >> 16) << 8));
        __builtin_amdgcn_sched_barrier(0);
#pragma unroll
        for (int c = 0; c < 16; ++c)
            acc += c_[c] * splat8(__builtin_bit_cast(_Float16, (unsigned short)(q_[c] & 0xffffu)));
    }

    // ---------- acc -> swizzled LDS tile ----------------------------------
    {
        const int cbyte = (h * 32 + d8) * 2;                      // 16B aligned
        const int wbyte = bql * 512 + (cbyte ^ ((bql & 7) << 4));
        *(half8*)(accT + (wbyte >> 1)) = acc;
    }
    __syncthreads();

    // ---------- output GEMM: 16x256 @ wto (fragment-major), bias, f32 store ---
    const int ml = lane & 15, q = lane >> 4;
    const int wc0 = wave * 32;                   // wave owns cols wc0..wc0+31
    const f32x4 zero4 = {0.f, 0.f, 0.f, 0.f};
    f32x4 o[2] = {zero4, zero4};

#pragma unroll
    for (int kt = 0; kt < 8; ++kt) {
        const int koff = kt * 64 + q * 16;       // byte k-offset in acc row
        const half8 af = *(const half8*)(accT +
            ((ml * 512 + (koff ^ ((ml & 7) << 4))) >> 1));
#pragma unroll
        for (int j = 0; j < 2; ++j) {
            // fragment-major: 1KB contiguous per wave-instruction
            const half8 bf = *(const half8*)(wto +
                ((((size_t)(wave * 2 + j) * 8 + kt) * 64 + lane) << 3));
            o[j] = __builtin_amdgcn_mfma_f32_16x16x32_f16(af, bf, o[j], 0, 0, 0);
        }
    }

    const int r0 = q * 4;
    const size_t bq0 = (size_t)L * 16;
#pragma unroll
    for (int j = 0; j < 2; ++j) {
        const int col = wc0 + j * 16 + ml;
        const float bj = b_out[col];
#pragma unroll
        for (int r = 0; r < 4; ++r)
            out[(bq0 + r0 + r) * 256 + col] = o[j][r] + bj;
    }
}

extern "C" void kernel_launch(void* const* d_in, const int* in_sizes, int n_in,
                              void* d_out, int out_size, void* d_ws, size_t ws_size,
                              hipStream_t stream) {
    const float* query  = (const float*)d_in[0];
    const float* refp   = (const float*)d_in[1];
    const float* value  = (const float*)d_in[2];
    const float* W_off  = (const float*)d_in[3];
    const float* b_off  = (const float*)d_in[4];
    const float* W_attn = (const float*)d_in[5];
    const float* b_attn = (const float*)d_in[6];
    const float* W_val  = (const float*)d_in[7];
    const float* b_val  = (const float*)d_in[8];
    const float* W_out  = (const float*)d_in[9];
    const float* b_out  = (const float*)d_in[10];
    float* out = (float*)d_out;

    const size_t M = M_TOTAL;

    _Float16* valh  = (_Float16*)d_ws;                // M*256
    _Float16* offh  = valh + M * 256;                 // M*384
    _Float16* wto   = offh + M * 384;                 // 8192 slots * 8 = 65536
    _Float16* wtf   = wto + 256 * 256;                // 10 tiles * 32KB = 327680 B

    dim3 blk(256);
    prep_w<<<dim3(112), blk, 0, stream>>>(W_val, W_off, W_attn, W_out, wtf, wto);
    gemm12_cvt<<<dim3(3400), blk, 0, stream>>>(
        value, query, wtf, b_val, b_off, b_attn, valh, offh);
    sample_out<<<dim3(M / 16), dim3(512), 0, stream>>>(
        valh, refp, offh, wto, b_out, out);
}